// Round 6
// baseline (519.513 us; speedup 1.0000x reference)
//
#include <hip/hip_runtime.h>
#include <hip/hip_fp16.h>
#include <math.h>

typedef _Float16 f16;
typedef __attribute__((ext_vector_type(8))) _Float16 f16x8;
typedef __attribute__((ext_vector_type(4))) _Float16 f16x4;
typedef __attribute__((ext_vector_type(4))) float f32x4;

#define NB 16
#define NN 2048
#define ND 256
#define KVB 32
#define QB 128   // q rows per 4-wave block (32 per wave)

__device__ __forceinline__ void gll16(const void* g, void* l) {
    __builtin_amdgcn_global_load_lds(
        (const __attribute__((address_space(1))) unsigned int*)g,
        (__attribute__((address_space(3))) unsigned int*)l, 16, 0, 0);
}

__device__ __forceinline__ long long len_at(const int* lenp, int b, bool is64) {
    return is64 ? ((const long long*)lenp)[b] : (long long)lenp[b];
}

// ---------------- pre-pass: X fp32 -> Xh f16 [b][n][d] + Xt f16 [b][d][n] ----
__global__ __launch_bounds__(256)
void prep(const float* __restrict__ X, f16* __restrict__ Xh, f16* __restrict__ Xt)
{
    const int b  = blockIdx.z;
    const int n0 = blockIdx.x * 64;
    const int d0 = blockIdx.y * 64;
    const int t  = threadIdx.x;
    __shared__ f16 T[64][72];

    const float* Xb  = X  + ((size_t)b*NN + n0)*ND + d0;
    f16*         Xhb = Xh + ((size_t)b*NN + n0)*ND + d0;
    #pragma unroll
    for (int it = 0; it < 4; ++it) {
        int r  = it*16 + (t >> 4);
        int c4 = t & 15;
        float4 v = *(const float4*)(Xb + (size_t)r*ND + c4*4);
        f16x4 h; h[0]=(f16)v.x; h[1]=(f16)v.y; h[2]=(f16)v.z; h[3]=(f16)v.w;
        *(f16x4*)&Xhb[(size_t)r*ND + c4*4] = h;
        *(f16x4*)&T[r][c4*4] = h;
    }
    __syncthreads();
    f16* Xtb = Xt + ((size_t)b*ND + d0)*NN + n0;
    #pragma unroll
    for (int it = 0; it < 2; ++it) {
        int id = it*256 + t;
        int dr = id >> 3;
        int ch = id & 7;
        f16x8 v;
        #pragma unroll
        for (int u = 0; u < 8; ++u) v[u] = T[ch*8+u][dr];
        *(f16x8*)&Xtb[(size_t)dr*NN + ch*8] = v;
    }
}

// ---------------- main flash-attention: 4 waves x 32q each, frag-order LDS --
// LDS layouts (16B slots), identical to round-5 kernel:
//   K:  byte kk*2048 + j*64 + g*16  holds K[j][d = kk*32 + g*8 + i]
//   Vt: byte dt*1024 + c*64 + g*16  holds V[j = g*8 + i][d = dt*16 + c]
// Each wave computes TWO 16-row q-subtiles off the same frag reads
// -> 32 FLOP per LDS byte (2x round-5).
__global__ __launch_bounds__(256, 2)
void attn5(const f16* __restrict__ Xh, const f16* __restrict__ Xt,
           const int* __restrict__ lenp, float* __restrict__ out)
{
    const int tid  = threadIdx.x;
    const int lane = tid & 63;
    const int w = tid >> 6;
    const int g = lane >> 4;
    const int c = lane & 15;

    // ---- LPT + XCD-paired job mapping (256 blocks = 16 qt x 16 b) ----
    const bool is64 = (lenp[1] == 0);
    long long Lv[NB];
    #pragma unroll
    for (int i = 0; i < NB; ++i) Lv[i] = len_at(lenp, i, is64);
    const int x = blockIdx.x & 7;
    const int k = blockIdx.x >> 3;        // 0..31
    const int wanted = (k < 16) ? x : (15 - x);
    const int qt = k & 15;
    int bsel = 0; long long Lb = 1;
    #pragma unroll
    for (int bb = 0; bb < NB; ++bb) {
        int rk = 0;
        #pragma unroll
        for (int b2 = 0; b2 < NB; ++b2)
            rk += (Lv[b2] > Lv[bb]) || (Lv[b2] == Lv[bb] && b2 < bb);
        if (rk == wanted) { bsel = bb; Lb = Lv[bb]; }
    }
    const int nt = (int)((Lb + KVB - 1) / KVB);

    __shared__ f16 Kl[2][8192];      // 2 x 16KB
    __shared__ f16 Vl[2][8192];      // 2 x 16KB
    __shared__ f16 Pl[4][2][16*36];  // per-wave, per-qsub P round-trip (72B rows)

    const char* xhb = (const char*)(Xh + (size_t)bsel*NN*ND);
    const char* xtb = (const char*)(Xt + (size_t)bsel*ND*NN);

    // ---- Q fragments: two 16-row subtiles per wave ----
    f16x8 qfA[8], qfB[8];
    {
        const char* qpA = xhb + (size_t)(qt*QB + w*32 + c)*512 + g*16;
        const char* qpB = qpA + 16*512;
        #pragma unroll
        for (int kk = 0; kk < 8; ++kk) {
            qfA[kk] = *(const f16x8*)(qpA + kk*64);
            qfB[kk] = *(const f16x8*)(qpB + kk*64);
        }
    }

    // ---- staging: 4 gll K + 4 gll V per thread per tile ----
    auto stage = [&](int buf, int kv0) {
        char* kb = (char*)&Kl[buf][0];
        char* vb = (char*)&Vl[buf][0];
        #pragma unroll
        for (int it = 0; it < 4; ++it) {
            int S  = it*256 + tid;
            int kk = S >> 7, j = (S >> 2) & 31, gg = S & 3;
            gll16(xhb + (size_t)(kv0 + j)*512 + kk*64 + gg*16, kb + S*16);
        }
        #pragma unroll
        for (int it = 0; it < 4; ++it) {
            int T  = it*256 + tid;
            int dt = T >> 6, cc = (T >> 2) & 15, gg = T & 3;
            gll16(xtb + (size_t)(dt*16 + cc)*4096 + (size_t)(kv0 + gg*8)*2, vb + T*16);
        }
    };

    f32x4 oA[16], oB[16];
    #pragma unroll
    for (int dt = 0; dt < 16; ++dt) {
        oA[dt] = (f32x4){0.f,0.f,0.f,0.f};
        oB[dt] = (f32x4){0.f,0.f,0.f,0.f};
    }
    float mA[4] = {-INFINITY,-INFINITY,-INFINITY,-INFINITY};
    float mB[4] = {-INFINITY,-INFINITY,-INFINITY,-INFINITY};
    float lA[4] = {0.f,0.f,0.f,0.f};
    float lB[4] = {0.f,0.f,0.f,0.f};

    // softmax + P-roundtrip for one q-subtile; returns PV A-frag
    auto smax = [&](f32x4& s0, f32x4& s1, float* m, float* l, f32x4* o,
                    f16* pw) -> f16x8 {
        float mx[4], mn[4], sc[4], p0[4], p1[4], rs[4];
        #pragma unroll
        for (int r = 0; r < 4; ++r) mx[r] = fmaxf(s0[r], s1[r]);
        #pragma unroll
        for (int off = 8; off >= 1; off >>= 1) {
            #pragma unroll
            for (int r = 0; r < 4; ++r)
                mx[r] = fmaxf(mx[r], __shfl_xor(mx[r], off, 64));
        }
        #pragma unroll
        for (int r = 0; r < 4; ++r) {
            mn[r] = fmaxf(m[r], mx[r]);
            sc[r] = __expf(m[r] - mn[r]);
            p0[r] = __expf(s0[r] - mn[r]);
            p1[r] = __expf(s1[r] - mn[r]);
            rs[r] = p0[r] + p1[r];
        }
        #pragma unroll
        for (int off = 8; off >= 1; off >>= 1) {
            #pragma unroll
            for (int r = 0; r < 4; ++r)
                rs[r] += __shfl_xor(rs[r], off, 64);
        }
        bool chg = (sc[0]!=1.f) | (sc[1]!=1.f) | (sc[2]!=1.f) | (sc[3]!=1.f);
        if (__any(chg)) {
            #pragma unroll
            for (int dt = 0; dt < 16; ++dt) {
                o[dt][0]*=sc[0]; o[dt][1]*=sc[1]; o[dt][2]*=sc[2]; o[dt][3]*=sc[3];
            }
        }
        #pragma unroll
        for (int r = 0; r < 4; ++r) { l[r] = l[r]*sc[r] + rs[r]; m[r] = mn[r]; }
        #pragma unroll
        for (int r = 0; r < 4; ++r) {
            pw[(g*4+r)*36 + c]      = (f16)p0[r];
            pw[(g*4+r)*36 + 16 + c] = (f16)p1[r];
        }
        union { f16x4 h[2]; f16x8 v; } pu;
        pu.h[0] = *(const f16x4*)(pw + c*36 + g*8);
        pu.h[1] = *(const f16x4*)(pw + c*36 + g*8 + 4);
        return pu.v;
    };

    // ---- prologue: tiles 0 and 1 in flight ----
    stage(0, 0);
    if (nt > 1) stage(1, KVB);

    for (int t = 0; t < nt; ++t) {
        const int kv0 = t * KVB;
        const int buf = t & 1;

        if (t + 1 < nt) { asm volatile("s_waitcnt vmcnt(8)" ::: "memory"); }
        else            { asm volatile("s_waitcnt vmcnt(0)" ::: "memory"); }
        __builtin_amdgcn_s_barrier();      // all waves' tile-t slices landed

        const char* kb = (const char*)&Kl[buf][0];
        const char* vb = (const char*)&Vl[buf][0];

        // ---- QK^T: two q-subtiles share each K-frag read ----
        f32x4 s0a = (f32x4){0.f,0.f,0.f,0.f};
        f32x4 s1a = (f32x4){0.f,0.f,0.f,0.f};
        f32x4 s0b = (f32x4){0.f,0.f,0.f,0.f};
        f32x4 s1b = (f32x4){0.f,0.f,0.f,0.f};
        __builtin_amdgcn_s_setprio(1);
        #pragma unroll
        for (int kk = 0; kk < 8; ++kk) {
            f16x8 b0 = *(const f16x8*)(kb + kk*2048        + c*64 + g*16);
            f16x8 b1 = *(const f16x8*)(kb + kk*2048 + 1024 + c*64 + g*16);
            s0a = __builtin_amdgcn_mfma_f32_16x16x32_f16(qfA[kk], b0, s0a, 0, 0, 0);
            s0b = __builtin_amdgcn_mfma_f32_16x16x32_f16(qfB[kk], b0, s0b, 0, 0, 0);
            s1a = __builtin_amdgcn_mfma_f32_16x16x32_f16(qfA[kk], b1, s1a, 0, 0, 0);
            s1b = __builtin_amdgcn_mfma_f32_16x16x32_f16(qfB[kk], b1, s1b, 0, 0, 0);
        }
        __builtin_amdgcn_s_setprio(0);

        const float NEG = -1e30f;
        if (kv0 + c >= Lb) {
            s0a[0]=NEG; s0a[1]=NEG; s0a[2]=NEG; s0a[3]=NEG;
            s0b[0]=NEG; s0b[1]=NEG; s0b[2]=NEG; s0b[3]=NEG;
        }
        if (kv0 + 16 + c >= Lb) {
            s1a[0]=NEG; s1a[1]=NEG; s1a[2]=NEG; s1a[3]=NEG;
            s1b[0]=NEG; s1b[1]=NEG; s1b[2]=NEG; s1b[3]=NEG;
        }

        f16x8 pfA = smax(s0a, s1a, mA, lA, oA, &Pl[w][0][0]);
        f16x8 pfB = smax(s0b, s1b, mB, lB, oB, &Pl[w][1][0]);

        // ---- PV: both q-subtiles share each V-frag read ----
        __builtin_amdgcn_s_setprio(1);
        #pragma unroll
        for (int dt = 0; dt < 16; ++dt) {
            f16x8 vf = *(const f16x8*)(vb + dt*1024 + c*64 + g*16);
            oA[dt] = __builtin_amdgcn_mfma_f32_16x16x32_f16(pfA, vf, oA[dt], 0, 0, 0);
            oB[dt] = __builtin_amdgcn_mfma_f32_16x16x32_f16(pfB, vf, oB[dt], 0, 0, 0);
        }
        __builtin_amdgcn_s_setprio(0);

        __builtin_amdgcn_s_barrier();      // everyone done reading buf
        if (t + 2 < nt) stage(buf, kv0 + 2*KVB);
    }

    // ---- epilogue ----
    float invA[4], invB[4];
    #pragma unroll
    for (int r = 0; r < 4; ++r) { invA[r] = 1.0f / lA[r]; invB[r] = 1.0f / lB[r]; }
    float* obA = out + ((size_t)bsel*NN + (size_t)(qt*QB + w*32 + g*4))*ND + c;
    float* obB = obA + (size_t)16*ND;
    #pragma unroll
    for (int r = 0; r < 4; ++r) {
        #pragma unroll
        for (int dt = 0; dt < 16; ++dt) {
            obA[(size_t)r*ND + dt*16] = oA[dt][r] * invA[r];
            obB[(size_t)r*ND + dt*16] = oB[dt][r] * invB[r];
        }
    }
}

// ---------------- fallback (round-1 kernel) if ws too small ----------------
__global__ __launch_bounds__(256, 2)
void attn_fb(const float* __restrict__ X,
             const int* __restrict__ lenp,
             float* __restrict__ out)
{
    const int b   = blockIdx.y;
    const int qt  = blockIdx.x;
    const int tid = threadIdx.x;
    const int lane = tid & 63;
    const int w = tid >> 6;
    const int g = lane >> 4;
    const int c = lane & 15;

    const bool is64 = (lenp[1] == 0);
    const long long Lb = len_at(lenp, b, is64);

    __shared__ f16 Kl[KVB][264];
    __shared__ f16 Vt2[ND][40];
    __shared__ f16 Pl[4][16][40];

    const float* Xb = X + (size_t)b * NN * ND;

    f16x8 qf[8];
    {
        const float* qp = Xb + (size_t)(qt*64 + w*16 + c) * ND + g*8;
        #pragma unroll
        for (int kk = 0; kk < 8; ++kk) {
            float4 a = *(const float4*)(qp + kk*32);
            float4 d = *(const float4*)(qp + kk*32 + 4);
            f16x8 v;
            v[0]=(f16)a.x; v[1]=(f16)a.y; v[2]=(f16)a.z; v[3]=(f16)a.w;
            v[4]=(f16)d.x; v[5]=(f16)d.y; v[6]=(f16)d.z; v[7]=(f16)d.w;
            qf[kk] = v;
        }
    }

    f32x4 o[16];
    #pragma unroll
    for (int dt = 0; dt < 16; ++dt) o[dt] = (f32x4){0.f,0.f,0.f,0.f};
    float m[4] = {-INFINITY,-INFINITY,-INFINITY,-INFINITY};
    float lr[4] = {0.f,0.f,0.f,0.f};

    const int ntiles = (int)((Lb + KVB - 1) / KVB);
    for (int t = 0; t < ntiles; ++t) {
        const int kv0 = t * KVB;
        __syncthreads();
        #pragma unroll
        for (int it = 0; it < 8; ++it) {
            int idx4 = it*256 + tid;
            int row  = idx4 >> 6;
            int c4   = idx4 & 63;
            float4 v = *(const float4*)(Xb + (size_t)(kv0 + row)*ND + c4*4);
            f16x4 hh; hh[0]=(f16)v.x; hh[1]=(f16)v.y; hh[2]=(f16)v.z; hh[3]=(f16)v.w;
            *(f16x4*)&Kl[row][c4*4] = hh;
        }
        {
            const float* cp = Xb + (size_t)kv0*ND + tid;
            #pragma unroll
            for (int kq = 0; kq < 8; ++kq) {
                f16x4 hh;
                #pragma unroll
                for (int u = 0; u < 4; ++u) hh[u] = (f16)cp[(size_t)(kq*4+u)*ND];
                *(f16x4*)&Vt2[tid][kq*4] = hh;
            }
        }
        __syncthreads();

        f32x4 s0 = (f32x4){0.f,0.f,0.f,0.f};
        f32x4 s1 = (f32x4){0.f,0.f,0.f,0.f};
        #pragma unroll
        for (int kk = 0; kk < 8; ++kk) {
            f16x8 b0 = *(const f16x8*)&Kl[c     ][kk*32 + g*8];
            f16x8 b1 = *(const f16x8*)&Kl[16 + c][kk*32 + g*8];
            s0 = __builtin_amdgcn_mfma_f32_16x16x32_f16(qf[kk], b0, s0, 0, 0, 0);
            s1 = __builtin_amdgcn_mfma_f32_16x16x32_f16(qf[kk], b1, s1, 0, 0, 0);
        }

        const float NEG = -1e30f;
        if (kv0 + c >= Lb)      { s0[0]=NEG; s0[1]=NEG; s0[2]=NEG; s0[3]=NEG; }
        if (kv0 + 16 + c >= Lb) { s1[0]=NEG; s1[1]=NEG; s1[2]=NEG; s1[3]=NEG; }

        float mx[4], mn[4], sc[4], p0[4], p1[4], rs[4];
        #pragma unroll
        for (int r = 0; r < 4; ++r) mx[r] = fmaxf(s0[r], s1[r]);
        #pragma unroll
        for (int off = 8; off >= 1; off >>= 1) {
            #pragma unroll
            for (int r = 0; r < 4; ++r)
                mx[r] = fmaxf(mx[r], __shfl_xor(mx[r], off, 64));
        }
        #pragma unroll
        for (int r = 0; r < 4; ++r) {
            mn[r] = fmaxf(m[r], mx[r]);
            sc[r] = __expf(m[r] - mn[r]);
            p0[r] = __expf(s0[r] - mn[r]);
            p1[r] = __expf(s1[r] - mn[r]);
            rs[r] = p0[r] + p1[r];
        }
        #pragma unroll
        for (int off = 8; off >= 1; off >>= 1) {
            #pragma unroll
            for (int r = 0; r < 4; ++r)
                rs[r] += __shfl_xor(rs[r], off, 64);
        }
        bool chg = (sc[0]!=1.f) | (sc[1]!=1.f) | (sc[2]!=1.f) | (sc[3]!=1.f);
        if (__any(chg)) {
            #pragma unroll
            for (int dt = 0; dt < 16; ++dt) {
                o[dt][0]*=sc[0]; o[dt][1]*=sc[1]; o[dt][2]*=sc[2]; o[dt][3]*=sc[3];
            }
        }
        #pragma unroll
        for (int r = 0; r < 4; ++r) { lr[r] = lr[r]*sc[r] + rs[r]; m[r] = mn[r]; }

        #pragma unroll
        for (int r = 0; r < 4; ++r) {
            Pl[w][g*4+r][c]      = (f16)p0[r];
            Pl[w][g*4+r][16 + c] = (f16)p1[r];
        }
        f16x8 pf = *(const f16x8*)&Pl[w][c][g*8];

        #pragma unroll
        for (int dt = 0; dt < 16; ++dt) {
            f16x8 vf = *(const f16x8*)&Vt2[dt*16 + c][g*8];
            o[dt] = __builtin_amdgcn_mfma_f32_16x16x32_f16(pf, vf, o[dt], 0, 0, 0);
        }
    }

    float inv[4];
    #pragma unroll
    for (int r = 0; r < 4; ++r) inv[r] = 1.0f / lr[r];
    float* ob = out + ((size_t)b*NN + (size_t)(qt*64 + w*16 + g*4))*ND + c;
    #pragma unroll
    for (int r = 0; r < 4; ++r) {
        #pragma unroll
        for (int dt = 0; dt < 16; ++dt)
            ob[(size_t)r*ND + dt*16] = o[dt][r] * inv[r];
    }
}

extern "C" void kernel_launch(void* const* d_in, const int* in_sizes, int n_in,
                              void* d_out, int out_size, void* d_ws, size_t ws_size,
                              hipStream_t stream) {
    const float* X    = (const float*)d_in[0];
    const int*   lenp = (const int*)d_in[1];
    float*       out  = (float*)d_out;

    const size_t need = (size_t)NB * NN * ND * 2 /*f16*/ * 2 /*Xh+Xt*/;
    if (ws_size >= need) {
        f16* Xh = (f16*)d_ws;
        f16* Xt = Xh + (size_t)NB * NN * ND;
        hipLaunchKernelGGL(prep, dim3(NN/64, ND/64, NB), dim3(256), 0, stream, X, Xh, Xt);
        hipLaunchKernelGGL(attn5, dim3((NN/QB) * NB), dim3(256), 0, stream, Xh, Xt, lenp, out);
    } else {
        hipLaunchKernelGGL(attn_fb, dim3(NN/64, NB), dim3(256), 0, stream, X, lenp, out);
    }
}

// Round 7
// 317.520 us; speedup vs baseline: 1.6362x; 1.6362x over previous
//
#include <hip/hip_runtime.h>
#include <hip/hip_fp16.h>
#include <math.h>

typedef _Float16 f16;
typedef __attribute__((ext_vector_type(8))) _Float16 f16x8;
typedef __attribute__((ext_vector_type(4))) _Float16 f16x4;
typedef __attribute__((ext_vector_type(4))) float f32x4;

#define NB 16
#define NN 2048
#define ND 256
#define KVB 32
#define QB 64

__device__ __forceinline__ void gll16(const void* g, void* l) {
    __builtin_amdgcn_global_load_lds(
        (const __attribute__((address_space(1))) unsigned int*)g,
        (__attribute__((address_space(3))) unsigned int*)l, 16, 0, 0);
}

__device__ __forceinline__ long long len_at(const int* lenp, int b, bool is64) {
    return is64 ? ((const long long*)lenp)[b] : (long long)lenp[b];
}

// ---------------- pre-pass: X fp32 -> Xh f16 [b][n][d] + Xt f16 [b][d][n] ----
__global__ __launch_bounds__(256)
void prep(const float* __restrict__ X, f16* __restrict__ Xh, f16* __restrict__ Xt)
{
    const int b  = blockIdx.z;
    const int n0 = blockIdx.x * 64;
    const int d0 = blockIdx.y * 64;
    const int t  = threadIdx.x;
    __shared__ f16 T[64][72];

    const float* Xb  = X  + ((size_t)b*NN + n0)*ND + d0;
    f16*         Xhb = Xh + ((size_t)b*NN + n0)*ND + d0;
    #pragma unroll
    for (int it = 0; it < 4; ++it) {
        int r  = it*16 + (t >> 4);
        int c4 = t & 15;
        float4 v = *(const float4*)(Xb + (size_t)r*ND + c4*4);
        f16x4 h; h[0]=(f16)v.x; h[1]=(f16)v.y; h[2]=(f16)v.z; h[3]=(f16)v.w;
        *(f16x4*)&Xhb[(size_t)r*ND + c4*4] = h;
        *(f16x4*)&T[r][c4*4] = h;
    }
    __syncthreads();
    f16* Xtb = Xt + ((size_t)b*ND + d0)*NN + n0;
    #pragma unroll
    for (int it = 0; it < 2; ++it) {
        int id = it*256 + t;
        int dr = id >> 3;
        int ch = id & 7;
        f16x8 v;
        #pragma unroll
        for (int u = 0; u < 8; ++u) v[u] = T[ch*8+u][dr];
        *(f16x8*)&Xtb[(size_t)dr*NN + ch*8] = v;
    }
}

// ---------------- main flash-attention: 4-wave blocks, 4 blocks/CU ----------
// LDS layouts (16B slots), same frag-order as round-5 attn4:
//   K:  byte kk*2048 + j*64 + g*16  holds K[j][d = kk*32 + g*8 + i]
//   Vt: byte dt*1024 + c*64 + g*16  holds V[j = g*8 + i][d = dt*16 + c]
// Single-buffered K and V (36.5KB total) -> 4 blocks/CU = 16 waves/CU.
// 3-barrier split-stage pipeline keeps every load-use window >= ~500 cyc:
//   top: vmcnt(4) [K(t) ready] ; QK ; vmcnt(0) [V(t) ready, K fully read] ;
//   stage_k(t+1) ; softmax ; PV ; barrier ; stage_v(t+1)
__global__ __launch_bounds__(256, 4)
void attn6(const f16* __restrict__ Xh, const f16* __restrict__ Xt,
           const int* __restrict__ lenp, float* __restrict__ out)
{
    const int tid  = threadIdx.x;
    const int lane = tid & 63;
    const int w = tid >> 6;
    const int g = lane >> 4;
    const int c = lane & 15;

    // ---- LPT + XCD-paired job mapping ----
    const bool is64 = (lenp[1] == 0);
    long long Lv[NB];
    #pragma unroll
    for (int i = 0; i < NB; ++i) Lv[i] = len_at(lenp, i, is64);
    const int x = blockIdx.x & 7;         // XCD heuristic (blockIdx % 8)
    const int k = blockIdx.x >> 3;        // 0..63
    const int wanted = (k < 32) ? x : (15 - x);
    const int qt = k & 31;
    int bsel = 0; long long Lb = 1;
    #pragma unroll
    for (int bb = 0; bb < NB; ++bb) {
        int rk = 0;
        #pragma unroll
        for (int b2 = 0; b2 < NB; ++b2)
            rk += (Lv[b2] > Lv[bb]) || (Lv[b2] == Lv[bb] && b2 < bb);
        if (rk == wanted) { bsel = bb; Lb = Lv[bb]; }
    }
    const int nt = (int)((Lb + KVB - 1) / KVB);

    __shared__ f16 Kl[8192];        // 16KB single buffer
    __shared__ f16 Vl[8192];        // 16KB single buffer
    __shared__ f16 Pl[4][16*36];    // per-wave P round-trip, 72B rows

    const char* xhb = (const char*)(Xh + (size_t)bsel*NN*ND);
    const char* xtb = (const char*)(Xt + (size_t)bsel*ND*NN);

    // ---- Q fragments in registers ----
    f16x8 qf[8];
    {
        const char* qp = xhb + (size_t)(qt*QB + w*16 + c)*512 + g*16;
        #pragma unroll
        for (int kk = 0; kk < 8; ++kk) qf[kk] = *(const f16x8*)(qp + kk*64);
    }

    // ---- staging: 4 gll per thread per tile for each of K, V ----
    auto stage_k = [&](int kv0) {
        char* kb = (char*)&Kl[0];
        #pragma unroll
        for (int it = 0; it < 4; ++it) {
            int S  = it*256 + tid;
            int kk = S >> 7, j = (S >> 2) & 31, gg = S & 3;
            gll16(xhb + (size_t)(kv0 + j)*512 + kk*64 + gg*16, kb + S*16);
        }
    };
    auto stage_v = [&](int kv0) {
        char* vb = (char*)&Vl[0];
        #pragma unroll
        for (int it = 0; it < 4; ++it) {
            int T  = it*256 + tid;
            int dt = T >> 6, cc = (T >> 2) & 15, gg = T & 3;
            gll16(xtb + (size_t)(dt*16 + cc)*4096 + (size_t)(kv0 + gg*8)*2, vb + T*16);
        }
    };

    f32x4 o[16];
    #pragma unroll
    for (int dt = 0; dt < 16; ++dt) o[dt] = (f32x4){0.f,0.f,0.f,0.f};
    float m[4] = {-INFINITY,-INFINITY,-INFINITY,-INFINITY};
    float l[4] = {0.f,0.f,0.f,0.f};

    f16* pw = &Pl[w][0];

    // ---- prologue: tile 0 in flight (K first, then V) ----
    stage_k(0);
    stage_v(0);

    for (int t = 0; t < nt; ++t) {
        const int kv0 = t * KVB;

        asm volatile("s_waitcnt vmcnt(4)" ::: "memory");   // K(t) landed (own)
        __builtin_amdgcn_s_barrier();                      // K(t) ready block-wide

        const char* kb = (const char*)&Kl[0];
        const char* vb = (const char*)&Vl[0];

        // ---- QK^T: S[16q x 32j] in two 16x16 tiles ----
        f32x4 s0 = (f32x4){0.f,0.f,0.f,0.f};
        f32x4 s1 = (f32x4){0.f,0.f,0.f,0.f};
        __builtin_amdgcn_s_setprio(1);
        #pragma unroll
        for (int kk = 0; kk < 8; ++kk) {
            f16x8 b0 = *(const f16x8*)(kb + kk*2048        + c*64 + g*16);
            f16x8 b1 = *(const f16x8*)(kb + kk*2048 + 1024 + c*64 + g*16);
            s0 = __builtin_amdgcn_mfma_f32_16x16x32_f16(qf[kk], b0, s0, 0, 0, 0);
            s1 = __builtin_amdgcn_mfma_f32_16x16x32_f16(qf[kk], b1, s1, 0, 0, 0);
        }
        __builtin_amdgcn_s_setprio(0);

        asm volatile("s_waitcnt vmcnt(0)" ::: "memory");   // V(t) landed (own)
        __builtin_amdgcn_s_barrier();                      // V ready + K fully read
        if (t + 1 < nt) stage_k(kv0 + KVB);                // overwrite K under softmax/PV

        const float NEG = -1e30f;
        if (kv0 + c >= Lb)      { s0[0]=NEG; s0[1]=NEG; s0[2]=NEG; s0[3]=NEG; }
        if (kv0 + 16 + c >= Lb) { s1[0]=NEG; s1[1]=NEG; s1[2]=NEG; s1[3]=NEG; }

        // ---- online softmax with defer-max (THR=8) ----
        float mx[4], p0[4], p1[4], rs[4];
        #pragma unroll
        for (int r = 0; r < 4; ++r) mx[r] = fmaxf(s0[r], s1[r]);
        #pragma unroll
        for (int off = 8; off >= 1; off >>= 1) {
            #pragma unroll
            for (int r = 0; r < 4; ++r)
                mx[r] = fmaxf(mx[r], __shfl_xor(mx[r], off, 64));
        }
        bool need = (mx[0] > m[0]+8.f) | (mx[1] > m[1]+8.f) |
                    (mx[2] > m[2]+8.f) | (mx[3] > m[3]+8.f);
        if (__any(need)) {
            float mn[4], sc[4];
            #pragma unroll
            for (int r = 0; r < 4; ++r) {
                mn[r] = fmaxf(m[r], mx[r]);
                sc[r] = __expf(m[r] - mn[r]);
                m[r]  = mn[r];
                l[r] *= sc[r];
            }
            #pragma unroll
            for (int dt = 0; dt < 16; ++dt) {
                o[dt][0]*=sc[0]; o[dt][1]*=sc[1]; o[dt][2]*=sc[2]; o[dt][3]*=sc[3];
            }
        }
        #pragma unroll
        for (int r = 0; r < 4; ++r) {
            p0[r] = __expf(s0[r] - m[r]);     // bounded by e^8
            p1[r] = __expf(s1[r] - m[r]);
            rs[r] = p0[r] + p1[r];
        }
        #pragma unroll
        for (int off = 8; off >= 1; off >>= 1) {
            #pragma unroll
            for (int r = 0; r < 4; ++r)
                rs[r] += __shfl_xor(rs[r], off, 64);
        }
        #pragma unroll
        for (int r = 0; r < 4; ++r) l[r] += rs[r];

        // ---- P round-trip (C-layout -> A-layout), 72B rows ----
        #pragma unroll
        for (int r = 0; r < 4; ++r) {
            pw[(g*4+r)*36 + c]      = (f16)p0[r];
            pw[(g*4+r)*36 + 16 + c] = (f16)p1[r];
        }
        union { f16x4 h[2]; f16x8 v; } pu;
        pu.h[0] = *(const f16x4*)(pw + c*36 + g*8);
        pu.h[1] = *(const f16x4*)(pw + c*36 + g*8 + 4);
        f16x8 pf = pu.v;

        // ---- PV: O[16q x 256d] += P(16x32) x V(32x16) per d-tile ----
        __builtin_amdgcn_s_setprio(1);
        #pragma unroll
        for (int dt = 0; dt < 16; ++dt) {
            f16x8 vf = *(const f16x8*)(vb + dt*1024 + c*64 + g*16);
            o[dt] = __builtin_amdgcn_mfma_f32_16x16x32_f16(pf, vf, o[dt], 0, 0, 0);
        }
        __builtin_amdgcn_s_setprio(0);

        asm volatile("" ::: "memory");
        __builtin_amdgcn_s_barrier();                      // all done reading V(t)
        if (t + 1 < nt) stage_v(kv0 + KVB);
    }

    // ---- epilogue ----
    float inv[4];
    #pragma unroll
    for (int r = 0; r < 4; ++r) inv[r] = 1.0f / l[r];
    float* ob = out + ((size_t)bsel*NN + (size_t)(qt*QB + w*16 + g*4))*ND + c;
    #pragma unroll
    for (int r = 0; r < 4; ++r) {
        #pragma unroll
        for (int dt = 0; dt < 16; ++dt)
            ob[(size_t)r*ND + dt*16] = o[dt][r] * inv[r];
    }
}

// ---------------- fallback (round-1 kernel) if ws too small ----------------
__global__ __launch_bounds__(256, 2)
void attn_fb(const float* __restrict__ X,
             const int* __restrict__ lenp,
             float* __restrict__ out)
{
    const int b   = blockIdx.y;
    const int qt  = blockIdx.x;
    const int tid = threadIdx.x;
    const int lane = tid & 63;
    const int w = tid >> 6;
    const int g = lane >> 4;
    const int c = lane & 15;

    const bool is64 = (lenp[1] == 0);
    const long long Lb = len_at(lenp, b, is64);

    __shared__ f16 Kl[KVB][264];
    __shared__ f16 Vt2[ND][40];
    __shared__ f16 Pl[4][16][40];

    const float* Xb = X + (size_t)b * NN * ND;

    f16x8 qf[8];
    {
        const float* qp = Xb + (size_t)(qt*64 + w*16 + c) * ND + g*8;
        #pragma unroll
        for (int kk = 0; kk < 8; ++kk) {
            float4 a = *(const float4*)(qp + kk*32);
            float4 d = *(const float4*)(qp + kk*32 + 4);
            f16x8 v;
            v[0]=(f16)a.x; v[1]=(f16)a.y; v[2]=(f16)a.z; v[3]=(f16)a.w;
            v[4]=(f16)d.x; v[5]=(f16)d.y; v[6]=(f16)d.z; v[7]=(f16)d.w;
            qf[kk] = v;
        }
    }

    f32x4 o[16];
    #pragma unroll
    for (int dt = 0; dt < 16; ++dt) o[dt] = (f32x4){0.f,0.f,0.f,0.f};
    float m[4] = {-INFINITY,-INFINITY,-INFINITY,-INFINITY};
    float lr[4] = {0.f,0.f,0.f,0.f};

    const int ntiles = (int)((Lb + KVB - 1) / KVB);
    for (int t = 0; t < ntiles; ++t) {
        const int kv0 = t * KVB;
        __syncthreads();
        #pragma unroll
        for (int it = 0; it < 8; ++it) {
            int idx4 = it*256 + tid;
            int row  = idx4 >> 6;
            int c4   = idx4 & 63;
            float4 v = *(const float4*)(Xb + (size_t)(kv0 + row)*ND + c4*4);
            f16x4 hh; hh[0]=(f16)v.x; hh[1]=(f16)v.y; hh[2]=(f16)v.z; hh[3]=(f16)v.w;
            *(f16x4*)&Kl[row][c4*4] = hh;
        }
        {
            const float* cp = Xb + (size_t)kv0*ND + tid;
            #pragma unroll
            for (int kq = 0; kq < 8; ++kq) {
                f16x4 hh;
                #pragma unroll
                for (int u = 0; u < 4; ++u) hh[u] = (f16)cp[(size_t)(kq*4+u)*ND];
                *(f16x4*)&Vt2[tid][kq*4] = hh;
            }
        }
        __syncthreads();

        f32x4 s0 = (f32x4){0.f,0.f,0.f,0.f};
        f32x4 s1 = (f32x4){0.f,0.f,0.f,0.f};
        #pragma unroll
        for (int kk = 0; kk < 8; ++kk) {
            f16x8 b0 = *(const f16x8*)&Kl[c     ][kk*32 + g*8];
            f16x8 b1 = *(const f16x8*)&Kl[16 + c][kk*32 + g*8];
            s0 = __builtin_amdgcn_mfma_f32_16x16x32_f16(qf[kk], b0, s0, 0, 0, 0);
            s1 = __builtin_amdgcn_mfma_f32_16x16x32_f16(qf[kk], b1, s1, 0, 0, 0);
        }

        const float NEG = -1e30f;
        if (kv0 + c >= Lb)      { s0[0]=NEG; s0[1]=NEG; s0[2]=NEG; s0[3]=NEG; }
        if (kv0 + 16 + c >= Lb) { s1[0]=NEG; s1[1]=NEG; s1[2]=NEG; s1[3]=NEG; }

        float mx[4], mn[4], sc[4], p0[4], p1[4], rs[4];
        #pragma unroll
        for (int r = 0; r < 4; ++r) mx[r] = fmaxf(s0[r], s1[r]);
        #pragma unroll
        for (int off = 8; off >= 1; off >>= 1) {
            #pragma unroll
            for (int r = 0; r < 4; ++r)
                mx[r] = fmaxf(mx[r], __shfl_xor(mx[r], off, 64));
        }
        #pragma unroll
        for (int r = 0; r < 4; ++r) {
            mn[r] = fmaxf(m[r], mx[r]);
            sc[r] = __expf(m[r] - mn[r]);
            p0[r] = __expf(s0[r] - mn[r]);
            p1[r] = __expf(s1[r] - mn[r]);
            rs[r] = p0[r] + p1[r];
        }
        #pragma unroll
        for (int off = 8; off >= 1; off >>= 1) {
            #pragma unroll
            for (int r = 0; r < 4; ++r)
                rs[r] += __shfl_xor(rs[r], off, 64);
        }
        bool chg = (sc[0]!=1.f) | (sc[1]!=1.f) | (sc[2]!=1.f) | (sc[3]!=1.f);
        if (__any(chg)) {
            #pragma unroll
            for (int dt = 0; dt < 16; ++dt) {
                o[dt][0]*=sc[0]; o[dt][1]*=sc[1]; o[dt][2]*=sc[2]; o[dt][3]*=sc[3];
            }
        }
        #pragma unroll
        for (int r = 0; r < 4; ++r) { lr[r] = lr[r]*sc[r] + rs[r]; m[r] = mn[r]; }

        #pragma unroll
        for (int r = 0; r < 4; ++r) {
            Pl[w][g*4+r][c]      = (f16)p0[r];
            Pl[w][g*4+r][16 + c] = (f16)p1[r];
        }
        f16x8 pf = *(const f16x8*)&Pl[w][c][g*8];

        #pragma unroll
        for (int dt = 0; dt < 16; ++dt) {
            f16x8 vf = *(const f16x8*)&Vt2[dt*16 + c][g*8];
            o[dt] = __builtin_amdgcn_mfma_f32_16x16x32_f16(pf, vf, o[dt], 0, 0, 0);
        }
    }

    float inv[4];
    #pragma unroll
    for (int r = 0; r < 4; ++r) inv[r] = 1.0f / lr[r];
    float* ob = out + ((size_t)b*NN + (size_t)(qt*64 + w*16 + g*4))*ND + c;
    #pragma unroll
    for (int r = 0; r < 4; ++r) {
        #pragma unroll
        for (int dt = 0; dt < 16; ++dt)
            ob[(size_t)r*ND + dt*16] = o[dt][r] * inv[r];
    }
}

extern "C" void kernel_launch(void* const* d_in, const int* in_sizes, int n_in,
                              void* d_out, int out_size, void* d_ws, size_t ws_size,
                              hipStream_t stream) {
    const float* X    = (const float*)d_in[0];
    const int*   lenp = (const int*)d_in[1];
    float*       out  = (float*)d_out;

    const size_t need = (size_t)NB * NN * ND * 2 /*f16*/ * 2 /*Xh+Xt*/;
    if (ws_size >= need) {
        f16* Xh = (f16*)d_ws;
        f16* Xt = Xh + (size_t)NB * NN * ND;
        hipLaunchKernelGGL(prep, dim3(NN/64, ND/64, NB), dim3(256), 0, stream, X, Xh, Xt);
        hipLaunchKernelGGL(attn6, dim3((NN/QB) * NB), dim3(256), 0, stream, Xh, Xt, lenp, out);
    } else {
        hipLaunchKernelGGL(attn_fb, dim3(NN/64, NB), dim3(256), 0, stream, X, lenp, out);
    }
}

// Round 8
// 125.012 us; speedup vs baseline: 4.1557x; 2.5399x over previous
//
#include <hip/hip_runtime.h>
#include <hip/hip_fp16.h>
#include <math.h>

typedef _Float16 f16;
typedef __attribute__((ext_vector_type(8))) _Float16 f16x8;
typedef __attribute__((ext_vector_type(4))) _Float16 f16x4;
typedef __attribute__((ext_vector_type(4))) float f32x4;

#define NB 16
#define NN 2048
#define ND 256
#define KVB 32
#define QB 64
#define XSZ ((size_t)NB * NN * ND)   // 8388608 elements

__device__ __forceinline__ void gll16(const void* g, void* l) {
    __builtin_amdgcn_global_load_lds(
        (const __attribute__((address_space(1))) unsigned int*)g,
        (__attribute__((address_space(3))) unsigned int*)l, 16, 0, 0);
}

__device__ __forceinline__ long long len_at(const int* lenp, int b, bool is64) {
    return is64 ? ((const long long*)lenp)[b] : (long long)lenp[b];
}

// ---------------- pre-pass: X fp32 -> Xh f16 [b][n][d] + Xt f16 [b][d][n] ----
__global__ __launch_bounds__(256)
void prep(const float* __restrict__ X, f16* __restrict__ Xh, f16* __restrict__ Xt)
{
    const int b  = blockIdx.z;
    const int n0 = blockIdx.x * 64;
    const int d0 = blockIdx.y * 64;
    const int t  = threadIdx.x;
    __shared__ f16 T[64][72];

    const float* Xb  = X  + ((size_t)b*NN + n0)*ND + d0;
    f16*         Xhb = Xh + ((size_t)b*NN + n0)*ND + d0;
    #pragma unroll
    for (int it = 0; it < 4; ++it) {
        int r  = it*16 + (t >> 4);
        int c4 = t & 15;
        float4 v = *(const float4*)(Xb + (size_t)r*ND + c4*4);
        f16x4 h; h[0]=(f16)v.x; h[1]=(f16)v.y; h[2]=(f16)v.z; h[3]=(f16)v.w;
        *(f16x4*)&Xhb[(size_t)r*ND + c4*4] = h;
        *(f16x4*)&T[r][c4*4] = h;
    }
    __syncthreads();
    f16* Xtb = Xt + ((size_t)b*ND + d0)*NN + n0;
    #pragma unroll
    for (int it = 0; it < 2; ++it) {
        int id = it*256 + t;
        int dr = id >> 3;
        int ch = id & 7;
        f16x8 v;
        #pragma unroll
        for (int u = 0; u < 8; ++u) v[u] = T[ch*8+u][dr];
        *(f16x8*)&Xtb[(size_t)dr*NN + ch*8] = v;
    }
}

// ---------------- split-KV flash kernel: 1024 blocks, 4 blocks/CU ----------
// Half h processes KV tiles t with t%2==h. Partials: normalized O (f16) +
// per-row logsumexp s = m + log(l) (f32). LDS 37.4KB single-buffered K,V with
// the 3-barrier split-stage pipeline (K-wait / QK / V-wait / stage_k(t+1) /
// softmax / PV / barrier / stage_v(t+1)).
__global__ __launch_bounds__(256, 2)
void attn7(const f16* __restrict__ Xh, const f16* __restrict__ Xt,
           const int* __restrict__ lenp,
           f16* __restrict__ Op, float* __restrict__ Sl)
{
    const int tid  = threadIdx.x;
    const int lane = tid & 63;
    const int w = tid >> 6;
    const int g = lane >> 4;
    const int c = lane & 15;

    // ---- job mapping: lin = ((k2*2 + half) << 3) | x ----
    const bool is64 = (lenp[1] == 0);
    long long Lv[NB];
    #pragma unroll
    for (int i = 0; i < NB; ++i) Lv[i] = len_at(lenp, i, is64);
    const int x   = blockIdx.x & 7;
    const int kk2 = blockIdx.x >> 3;      // 0..127
    const int h   = kk2 & 1;              // KV half (tile parity)
    const int k2  = kk2 >> 1;             // 0..63
    const int wanted = (k2 < 32) ? x : (15 - x);
    const int qt  = k2 & 31;
    int bsel = 0; long long Lb = 1;
    #pragma unroll
    for (int bb = 0; bb < NB; ++bb) {
        int rk = 0;
        #pragma unroll
        for (int b2 = 0; b2 < NB; ++b2)
            rk += (Lv[b2] > Lv[bb]) || (Lv[b2] == Lv[bb] && b2 < bb);
        if (rk == wanted) { bsel = bb; Lb = Lv[bb]; }
    }
    const int nt  = (int)((Lb + KVB - 1) / KVB);
    const int nth = (h == 0) ? ((nt + 1) >> 1) : (nt >> 1);
    if (nth == 0) return;                 // empty half (only possible for h=1)

    __shared__ f16 Kl[8192];        // 16KB single buffer
    __shared__ f16 Vl[8192];        // 16KB single buffer
    __shared__ f16 Pl[4][16*36];    // per-wave P round-trip, 72B rows

    const char* xhb = (const char*)(Xh + (size_t)bsel*NN*ND);
    const char* xtb = (const char*)(Xt + (size_t)bsel*ND*NN);

    // ---- Q fragments in registers ----
    f16x8 qf[8];
    {
        const char* qp = xhb + (size_t)(qt*QB + w*16 + c)*512 + g*16;
        #pragma unroll
        for (int kk = 0; kk < 8; ++kk) qf[kk] = *(const f16x8*)(qp + kk*64);
    }

    auto stage_k = [&](int kv0) {
        char* kb = (char*)&Kl[0];
        #pragma unroll
        for (int it = 0; it < 4; ++it) {
            int S  = it*256 + tid;
            int kk = S >> 7, j = (S >> 2) & 31, gg = S & 3;
            gll16(xhb + (size_t)(kv0 + j)*512 + kk*64 + gg*16, kb + S*16);
        }
    };
    auto stage_v = [&](int kv0) {
        char* vb = (char*)&Vl[0];
        #pragma unroll
        for (int it = 0; it < 4; ++it) {
            int T  = it*256 + tid;
            int dt = T >> 6, cc = (T >> 2) & 15, gg = T & 3;
            gll16(xtb + (size_t)(dt*16 + cc)*4096 + (size_t)(kv0 + gg*8)*2, vb + T*16);
        }
    };

    f32x4 o[16];
    #pragma unroll
    for (int dt = 0; dt < 16; ++dt) o[dt] = (f32x4){0.f,0.f,0.f,0.f};
    float m[4] = {-INFINITY,-INFINITY,-INFINITY,-INFINITY};
    float l[4] = {0.f,0.f,0.f,0.f};

    f16* pw = &Pl[w][0];

    stage_k(h*KVB);
    stage_v(h*KVB);

    for (int ti = 0; ti < nth; ++ti) {
        const int kv0 = (2*ti + h) * KVB;
        const bool more = (ti + 1 < nth);

        asm volatile("s_waitcnt vmcnt(4)" ::: "memory");   // own K(t) landed
        __builtin_amdgcn_s_barrier();                      // K ready block-wide

        const char* kb = (const char*)&Kl[0];
        const char* vb = (const char*)&Vl[0];

        // ---- QK^T ----
        f32x4 s0 = (f32x4){0.f,0.f,0.f,0.f};
        f32x4 s1 = (f32x4){0.f,0.f,0.f,0.f};
        __builtin_amdgcn_s_setprio(1);
        #pragma unroll
        for (int kk = 0; kk < 8; ++kk) {
            f16x8 b0 = *(const f16x8*)(kb + kk*2048        + c*64 + g*16);
            f16x8 b1 = *(const f16x8*)(kb + kk*2048 + 1024 + c*64 + g*16);
            s0 = __builtin_amdgcn_mfma_f32_16x16x32_f16(qf[kk], b0, s0, 0, 0, 0);
            s1 = __builtin_amdgcn_mfma_f32_16x16x32_f16(qf[kk], b1, s1, 0, 0, 0);
        }
        __builtin_amdgcn_s_setprio(0);

        asm volatile("s_waitcnt vmcnt(0)" ::: "memory");   // own V(t) landed
        __builtin_amdgcn_s_barrier();                      // V ready + K fully read
        if (more) stage_k(kv0 + 2*KVB);                    // overwrite K under SM/PV

        const float NEG = -1e30f;
        if (kv0 + c >= Lb)      { s0[0]=NEG; s0[1]=NEG; s0[2]=NEG; s0[3]=NEG; }
        if (kv0 + 16 + c >= Lb) { s1[0]=NEG; s1[1]=NEG; s1[2]=NEG; s1[3]=NEG; }

        // ---- online softmax with defer-max (THR=8) ----
        float mx[4], p0[4], p1[4], rs[4];
        #pragma unroll
        for (int r = 0; r < 4; ++r) mx[r] = fmaxf(s0[r], s1[r]);
        #pragma unroll
        for (int off = 8; off >= 1; off >>= 1) {
            #pragma unroll
            for (int r = 0; r < 4; ++r)
                mx[r] = fmaxf(mx[r], __shfl_xor(mx[r], off, 64));
        }
        bool need = (mx[0] > m[0]+8.f) | (mx[1] > m[1]+8.f) |
                    (mx[2] > m[2]+8.f) | (mx[3] > m[3]+8.f);
        if (__any(need)) {
            float mn[4], sc[4];
            #pragma unroll
            for (int r = 0; r < 4; ++r) {
                mn[r] = fmaxf(m[r], mx[r]);
                sc[r] = __expf(m[r] - mn[r]);
                m[r]  = mn[r];
                l[r] *= sc[r];
            }
            #pragma unroll
            for (int dt = 0; dt < 16; ++dt) {
                o[dt][0]*=sc[0]; o[dt][1]*=sc[1]; o[dt][2]*=sc[2]; o[dt][3]*=sc[3];
            }
        }
        #pragma unroll
        for (int r = 0; r < 4; ++r) {
            p0[r] = __expf(s0[r] - m[r]);
            p1[r] = __expf(s1[r] - m[r]);
            rs[r] = p0[r] + p1[r];
        }
        #pragma unroll
        for (int off = 8; off >= 1; off >>= 1) {
            #pragma unroll
            for (int r = 0; r < 4; ++r)
                rs[r] += __shfl_xor(rs[r], off, 64);
        }
        #pragma unroll
        for (int r = 0; r < 4; ++r) l[r] += rs[r];

        // ---- P round-trip (C-layout -> A-layout) ----
        #pragma unroll
        for (int r = 0; r < 4; ++r) {
            pw[(g*4+r)*36 + c]      = (f16)p0[r];
            pw[(g*4+r)*36 + 16 + c] = (f16)p1[r];
        }
        union { f16x4 hh[2]; f16x8 v; } pu;
        pu.hh[0] = *(const f16x4*)(pw + c*36 + g*8);
        pu.hh[1] = *(const f16x4*)(pw + c*36 + g*8 + 4);
        f16x8 pf = pu.v;

        // ---- PV ----
        __builtin_amdgcn_s_setprio(1);
        #pragma unroll
        for (int dt = 0; dt < 16; ++dt) {
            f16x8 vf = *(const f16x8*)(vb + dt*1024 + c*64 + g*16);
            o[dt] = __builtin_amdgcn_mfma_f32_16x16x32_f16(pf, vf, o[dt], 0, 0, 0);
        }
        __builtin_amdgcn_s_setprio(0);

        asm volatile("" ::: "memory");
        __builtin_amdgcn_s_barrier();                      // all done reading V(t)
        if (more) stage_v(kv0 + 2*KVB);
    }

    // ---- epilogue: normalized partial (f16) + per-row logsumexp (f32) ----
    float inv[4];
    #pragma unroll
    for (int r = 0; r < 4; ++r) inv[r] = 1.0f / l[r];
    f16* op = Op + (size_t)h*XSZ + ((size_t)bsel*NN + (size_t)(qt*QB + w*16 + g*4))*ND + c;
    #pragma unroll
    for (int r = 0; r < 4; ++r) {
        #pragma unroll
        for (int dt = 0; dt < 16; ++dt)
            op[(size_t)r*ND + dt*16] = (f16)(o[dt][r] * inv[r]);
    }
    if (c == 0) {
        float* sl = Sl + ((size_t)(h*NB + bsel))*NN + (size_t)(qt*QB + w*16 + g*4);
        #pragma unroll
        for (int r = 0; r < 4; ++r) sl[r] = m[r] + __logf(l[r]);
    }
}

// ---------------- merge: out = (O1 w1 + O2 w2) / (w1 + w2) ------------------
__global__ __launch_bounds__(256)
void merge(const f16* __restrict__ Op, const float* __restrict__ Sl,
           const int* __restrict__ lenp, float* __restrict__ out)
{
    const int tid = threadIdx.x;
    const int rg  = blockIdx.x * 8 + (tid >> 5);   // global row 0..32767
    const int b   = rg >> 11;
    const int q   = rg & 2047;
    const int d0  = (tid & 31) * 8;

    const bool is64 = (lenp[1] == 0);
    const long long Lb = len_at(lenp, b, is64);

    const f16* p1 = Op + ((size_t)b*NN + q)*ND + d0;
    f16x8 a1 = *(const f16x8*)p1;
    float r[8];
    if (Lb <= KVB) {
        #pragma unroll
        for (int i = 0; i < 8; ++i) r[i] = (float)a1[i];
    } else {
        f16x8 a2 = *(const f16x8*)(p1 + XSZ);
        float s1 = Sl[(size_t)b*NN + q];
        float s2 = Sl[(size_t)(NB + b)*NN + q];
        float sm = fmaxf(s1, s2);
        float w1 = __expf(s1 - sm), w2 = __expf(s2 - sm);
        float dn = 1.f / (w1 + w2);
        w1 *= dn; w2 *= dn;
        #pragma unroll
        for (int i = 0; i < 8; ++i) r[i] = (float)a1[i]*w1 + (float)a2[i]*w2;
    }
    float* ob = out + ((size_t)b*NN + q)*ND + d0;
    *(float4*)ob       = (float4){r[0], r[1], r[2], r[3]};
    *(float4*)(ob + 4) = (float4){r[4], r[5], r[6], r[7]};
}

// ---------------- mid-tier (round-5 attn4, proven 136us) --------------------
__global__ __launch_bounds__(256, 2)
void attn4(const f16* __restrict__ Xh, const f16* __restrict__ Xt,
           const int* __restrict__ lenp, float* __restrict__ out)
{
    const int tid  = threadIdx.x;
    const int lane = tid & 63;
    const int w = tid >> 6;
    const int g = lane >> 4;
    const int c = lane & 15;

    const bool is64 = (lenp[1] == 0);
    long long Lv[NB];
    #pragma unroll
    for (int i = 0; i < NB; ++i) Lv[i] = len_at(lenp, i, is64);
    const int x = blockIdx.x & 7;
    const int k = blockIdx.x >> 3;
    const int wanted = (k < 32) ? x : (15 - x);
    const int qt = k & 31;
    int bsel = 0; long long Lb = 1;
    #pragma unroll
    for (int bb = 0; bb < NB; ++bb) {
        int rk = 0;
        #pragma unroll
        for (int b2 = 0; b2 < NB; ++b2)
            rk += (Lv[b2] > Lv[bb]) || (Lv[b2] == Lv[bb] && b2 < bb);
        if (rk == wanted) { bsel = bb; Lb = Lv[bb]; }
    }
    const int nt = (int)((Lb + KVB - 1) / KVB);

    __shared__ f16 Kl[2][8192];
    __shared__ f16 Vl[2][8192];
    __shared__ f16 Pl[4][16*36];

    const char* xhb = (const char*)(Xh + (size_t)bsel*NN*ND);
    const char* xtb = (const char*)(Xt + (size_t)bsel*ND*NN);

    f16x8 qf[8];
    {
        const char* qp = xhb + (size_t)(qt*QB + w*16 + c)*512 + g*16;
        #pragma unroll
        for (int kk = 0; kk < 8; ++kk) qf[kk] = *(const f16x8*)(qp + kk*64);
    }

    auto stage = [&](int buf, int kv0) {
        char* kb = (char*)&Kl[buf][0];
        char* vb = (char*)&Vl[buf][0];
        #pragma unroll
        for (int it = 0; it < 4; ++it) {
            int S  = it*256 + tid;
            int kk = S >> 7, j = (S >> 2) & 31, gg = S & 3;
            gll16(xhb + (size_t)(kv0 + j)*512 + kk*64 + gg*16, kb + S*16);
        }
        #pragma unroll
        for (int it = 0; it < 4; ++it) {
            int T  = it*256 + tid;
            int dt = T >> 6, cc = (T >> 2) & 15, gg = T & 3;
            gll16(xtb + (size_t)(dt*16 + cc)*4096 + (size_t)(kv0 + gg*8)*2, vb + T*16);
        }
    };

    f32x4 o[16];
    #pragma unroll
    for (int dt = 0; dt < 16; ++dt) o[dt] = (f32x4){0.f,0.f,0.f,0.f};
    float m[4] = {-INFINITY,-INFINITY,-INFINITY,-INFINITY};
    float l[4] = {0.f,0.f,0.f,0.f};

    f16* pw = &Pl[w][0];

    stage(0, 0);
    if (nt > 1) stage(1, KVB);

    for (int t = 0; t < nt; ++t) {
        const int kv0 = t * KVB;
        const int buf = t & 1;

        if (t + 1 < nt) { asm volatile("s_waitcnt vmcnt(8)" ::: "memory"); }
        else            { asm volatile("s_waitcnt vmcnt(0)" ::: "memory"); }
        __builtin_amdgcn_s_barrier();

        const char* kb = (const char*)&Kl[buf][0];
        const char* vb = (const char*)&Vl[buf][0];

        f32x4 s0 = (f32x4){0.f,0.f,0.f,0.f};
        f32x4 s1 = (f32x4){0.f,0.f,0.f,0.f};
        #pragma unroll
        for (int kk = 0; kk < 8; ++kk) {
            f16x8 b0 = *(const f16x8*)(kb + kk*2048        + c*64 + g*16);
            f16x8 b1 = *(const f16x8*)(kb + kk*2048 + 1024 + c*64 + g*16);
            s0 = __builtin_amdgcn_mfma_f32_16x16x32_f16(qf[kk], b0, s0, 0, 0, 0);
            s1 = __builtin_amdgcn_mfma_f32_16x16x32_f16(qf[kk], b1, s1, 0, 0, 0);
        }

        const float NEG = -1e30f;
        if (kv0 + c >= Lb)      { s0[0]=NEG; s0[1]=NEG; s0[2]=NEG; s0[3]=NEG; }
        if (kv0 + 16 + c >= Lb) { s1[0]=NEG; s1[1]=NEG; s1[2]=NEG; s1[3]=NEG; }

        float mx[4], mn[4], sc[4], p0[4], p1[4], rs[4];
        #pragma unroll
        for (int r = 0; r < 4; ++r) mx[r] = fmaxf(s0[r], s1[r]);
        #pragma unroll
        for (int off = 8; off >= 1; off >>= 1) {
            #pragma unroll
            for (int r = 0; r < 4; ++r)
                mx[r] = fmaxf(mx[r], __shfl_xor(mx[r], off, 64));
        }
        #pragma unroll
        for (int r = 0; r < 4; ++r) {
            mn[r] = fmaxf(m[r], mx[r]);
            sc[r] = __expf(m[r] - mn[r]);
            p0[r] = __expf(s0[r] - mn[r]);
            p1[r] = __expf(s1[r] - mn[r]);
            rs[r] = p0[r] + p1[r];
        }
        #pragma unroll
        for (int off = 8; off >= 1; off >>= 1) {
            #pragma unroll
            for (int r = 0; r < 4; ++r)
                rs[r] += __shfl_xor(rs[r], off, 64);
        }
        bool chg = (sc[0]!=1.f) | (sc[1]!=1.f) | (sc[2]!=1.f) | (sc[3]!=1.f);
        if (__any(chg)) {
            #pragma unroll
            for (int dt = 0; dt < 16; ++dt) {
                o[dt][0]*=sc[0]; o[dt][1]*=sc[1]; o[dt][2]*=sc[2]; o[dt][3]*=sc[3];
            }
        }
        #pragma unroll
        for (int r = 0; r < 4; ++r) { l[r] = l[r]*sc[r] + rs[r]; m[r] = mn[r]; }

        #pragma unroll
        for (int r = 0; r < 4; ++r) {
            pw[(g*4+r)*36 + c]      = (f16)p0[r];
            pw[(g*4+r)*36 + 16 + c] = (f16)p1[r];
        }
        union { f16x4 hh[2]; f16x8 v; } pu;
        pu.hh[0] = *(const f16x4*)(pw + c*36 + g*8);
        pu.hh[1] = *(const f16x4*)(pw + c*36 + g*8 + 4);
        f16x8 pf = pu.v;

        #pragma unroll
        for (int dt = 0; dt < 16; ++dt) {
            f16x8 vf = *(const f16x8*)(vb + dt*1024 + c*64 + g*16);
            o[dt] = __builtin_amdgcn_mfma_f32_16x16x32_f16(pf, vf, o[dt], 0, 0, 0);
        }

        __builtin_amdgcn_s_barrier();
        if (t + 2 < nt) stage(buf, kv0 + 2*KVB);
    }

    float inv[4];
    #pragma unroll
    for (int r = 0; r < 4; ++r) inv[r] = 1.0f / l[r];
    float* ob = out + ((size_t)bsel*NN + (size_t)(qt*QB + w*16 + g*4))*ND + c;
    #pragma unroll
    for (int r = 0; r < 4; ++r) {
        #pragma unroll
        for (int dt = 0; dt < 16; ++dt)
            ob[(size_t)r*ND + dt*16] = o[dt][r] * inv[r];
    }
}

// ---------------- lowest tier (no workspace) --------------------------------
__global__ __launch_bounds__(256, 2)
void attn_fb(const float* __restrict__ X,
             const int* __restrict__ lenp,
             float* __restrict__ out)
{
    const int b   = blockIdx.y;
    const int qt  = blockIdx.x;
    const int tid = threadIdx.x;
    const int lane = tid & 63;
    const int w = tid >> 6;
    const int g = lane >> 4;
    const int c = lane & 15;

    const bool is64 = (lenp[1] == 0);
    const long long Lb = len_at(lenp, b, is64);

    __shared__ f16 Kl[KVB][264];
    __shared__ f16 Vt2[ND][40];
    __shared__ f16 Pl[4][16][40];

    const float* Xb = X + (size_t)b * NN * ND;

    f16x8 qf[8];
    {
        const float* qp = Xb + (size_t)(qt*64 + w*16 + c) * ND + g*8;
        #pragma unroll
        for (int kk = 0; kk < 8; ++kk) {
            float4 a = *(const float4*)(qp + kk*32);
            float4 d = *(const float4*)(qp + kk*32 + 4);
            f16x8 v;
            v[0]=(f16)a.x; v[1]=(f16)a.y; v[2]=(f16)a.z; v[3]=(f16)a.w;
            v[4]=(f16)d.x; v[5]=(f16)d.y; v[6]=(f16)d.z; v[7]=(f16)d.w;
            qf[kk] = v;
        }
    }

    f32x4 o[16];
    #pragma unroll
    for (int dt = 0; dt < 16; ++dt) o[dt] = (f32x4){0.f,0.f,0.f,0.f};
    float m[4] = {-INFINITY,-INFINITY,-INFINITY,-INFINITY};
    float lr[4] = {0.f,0.f,0.f,0.f};

    const int ntiles = (int)((Lb + KVB - 1) / KVB);
    for (int t = 0; t < ntiles; ++t) {
        const int kv0 = t * KVB;
        __syncthreads();
        #pragma unroll
        for (int it = 0; it < 8; ++it) {
            int idx4 = it*256 + tid;
            int row  = idx4 >> 6;
            int c4   = idx4 & 63;
            float4 v = *(const float4*)(Xb + (size_t)(kv0 + row)*ND + c4*4);
            f16x4 hh; hh[0]=(f16)v.x; hh[1]=(f16)v.y; hh[2]=(f16)v.z; hh[3]=(f16)v.w;
            *(f16x4*)&Kl[row][c4*4] = hh;
        }
        {
            const float* cp = Xb + (size_t)kv0*ND + tid;
            #pragma unroll
            for (int kq = 0; kq < 8; ++kq) {
                f16x4 hh;
                #pragma unroll
                for (int u = 0; u < 4; ++u) hh[u] = (f16)cp[(size_t)(kq*4+u)*ND];
                *(f16x4*)&Vt2[tid][kq*4] = hh;
            }
        }
        __syncthreads();

        f32x4 s0 = (f32x4){0.f,0.f,0.f,0.f};
        f32x4 s1 = (f32x4){0.f,0.f,0.f,0.f};
        #pragma unroll
        for (int kk = 0; kk < 8; ++kk) {
            f16x8 b0 = *(const f16x8*)&Kl[c     ][kk*32 + g*8];
            f16x8 b1 = *(const f16x8*)&Kl[16 + c][kk*32 + g*8];
            s0 = __builtin_amdgcn_mfma_f32_16x16x32_f16(qf[kk], b0, s0, 0, 0, 0);
            s1 = __builtin_amdgcn_mfma_f32_16x16x32_f16(qf[kk], b1, s1, 0, 0, 0);
        }

        const float NEG = -1e30f;
        if (kv0 + c >= Lb)      { s0[0]=NEG; s0[1]=NEG; s0[2]=NEG; s0[3]=NEG; }
        if (kv0 + 16 + c >= Lb) { s1[0]=NEG; s1[1]=NEG; s1[2]=NEG; s1[3]=NEG; }

        float mx[4], mn[4], sc[4], p0[4], p1[4], rs[4];
        #pragma unroll
        for (int r = 0; r < 4; ++r) mx[r] = fmaxf(s0[r], s1[r]);
        #pragma unroll
        for (int off = 8; off >= 1; off >>= 1) {
            #pragma unroll
            for (int r = 0; r < 4; ++r)
                mx[r] = fmaxf(mx[r], __shfl_xor(mx[r], off, 64));
        }
        #pragma unroll
        for (int r = 0; r < 4; ++r) {
            mn[r] = fmaxf(m[r], mx[r]);
            sc[r] = __expf(m[r] - mn[r]);
            p0[r] = __expf(s0[r] - mn[r]);
            p1[r] = __expf(s1[r] - mn[r]);
            rs[r] = p0[r] + p1[r];
        }
        #pragma unroll
        for (int off = 8; off >= 1; off >>= 1) {
            #pragma unroll
            for (int r = 0; r < 4; ++r)
                rs[r] += __shfl_xor(rs[r], off, 64);
        }
        bool chg = (sc[0]!=1.f) | (sc[1]!=1.f) | (sc[2]!=1.f) | (sc[3]!=1.f);
        if (__any(chg)) {
            #pragma unroll
            for (int dt = 0; dt < 16; ++dt) {
                o[dt][0]*=sc[0]; o[dt][1]*=sc[1]; o[dt][2]*=sc[2]; o[dt][3]*=sc[3];
            }
        }
        #pragma unroll
        for (int r = 0; r < 4; ++r) { lr[r] = lr[r]*sc[r] + rs[r]; m[r] = mn[r]; }

        #pragma unroll
        for (int r = 0; r < 4; ++r) {
            Pl[w][g*4+r][c]      = (f16)p0[r];
            Pl[w][g*4+r][16 + c] = (f16)p1[r];
        }
        f16x8 pf = *(const f16x8*)&Pl[w][c][g*8];

        #pragma unroll
        for (int dt = 0; dt < 16; ++dt) {
            f16x8 vf = *(const f16x8*)&Vt2[dt*16 + c][g*8];
            o[dt] = __builtin_amdgcn_mfma_f32_16x16x32_f16(pf, vf, o[dt], 0, 0, 0);
        }
    }

    float inv[4];
    #pragma unroll
    for (int r = 0; r < 4; ++r) inv[r] = 1.0f / lr[r];
    float* ob = out + ((size_t)b*NN + (size_t)(qt*64 + w*16 + g*4))*ND + c;
    #pragma unroll
    for (int r = 0; r < 4; ++r) {
        #pragma unroll
        for (int dt = 0; dt < 16; ++dt)
            ob[(size_t)r*ND + dt*16] = o[dt][r] * inv[r];
    }
}

extern "C" void kernel_launch(void* const* d_in, const int* in_sizes, int n_in,
                              void* d_out, int out_size, void* d_ws, size_t ws_size,
                              hipStream_t stream) {
    const float* X    = (const float*)d_in[0];
    const int*   lenp = (const int*)d_in[1];
    float*       out  = (float*)d_out;

    const size_t need_base  = XSZ * 2 * 2;                    // Xh + Xt (f16)
    const size_t need_split = need_base + XSZ * 2 * 2         // + Op[2] (f16)
                              + (size_t)2 * NB * NN * 4;      // + Sl (f32)
    if (ws_size >= need_split) {
        f16* Xh = (f16*)d_ws;
        f16* Xt = Xh + XSZ;
        f16* Op = Xt + XSZ;
        float* Sl = (float*)(Op + 2*XSZ);
        hipLaunchKernelGGL(prep, dim3(NN/64, ND/64, NB), dim3(256), 0, stream, X, Xh, Xt);
        hipLaunchKernelGGL(attn7, dim3(1024), dim3(256), 0, stream, Xh, Xt, lenp, Op, Sl);
        hipLaunchKernelGGL(merge, dim3(NB*NN/8), dim3(256), 0, stream, Op, Sl, lenp, out);
    } else if (ws_size >= need_base) {
        f16* Xh = (f16*)d_ws;
        f16* Xt = Xh + XSZ;
        hipLaunchKernelGGL(prep, dim3(NN/64, ND/64, NB), dim3(256), 0, stream, X, Xh, Xt);
        hipLaunchKernelGGL(attn4, dim3(512), dim3(256), 0, stream, Xh, Xt, lenp, out);
    } else {
        hipLaunchKernelGGL(attn_fb, dim3(NN/64, NB), dim3(256), 0, stream, X, lenp, out);
    }
}

// Round 9
// 96.568 us; speedup vs baseline: 5.3798x; 1.2946x over previous
//
#include <hip/hip_runtime.h>
#include <hip/hip_fp16.h>
#include <math.h>

typedef _Float16 f16;
typedef __attribute__((ext_vector_type(8))) _Float16 f16x8;
typedef __attribute__((ext_vector_type(4))) _Float16 f16x4;
typedef __attribute__((ext_vector_type(4))) float f32x4;

#define NB 16
#define NN 2048
#define ND 256
#define KVB 32
#define QB 64
#define XSZ ((size_t)NB * NN * ND)   // 8388608 elements

__device__ __forceinline__ void gll16(const void* g, void* l) {
    __builtin_amdgcn_global_load_lds(
        (const __attribute__((address_space(1))) unsigned int*)g,
        (__attribute__((address_space(3))) unsigned int*)l, 16, 0, 0);
}

__device__ __forceinline__ long long len_at(const int* lenp, int b, bool is64) {
    return is64 ? ((const long long*)lenp)[b] : (long long)lenp[b];
}

__device__ __forceinline__ float bperm_f(int src_lane, float v) {
    return __int_as_float(__builtin_amdgcn_ds_bpermute(src_lane * 4, __float_as_int(v)));
}

// ---------------- pre-pass: X fp32 -> Xh f16 [b][n][d] + Xt f16 [b][d][n] ----
__global__ __launch_bounds__(256)
void prep(const float* __restrict__ X, f16* __restrict__ Xh, f16* __restrict__ Xt)
{
    const int b  = blockIdx.z;
    const int n0 = blockIdx.x * 64;
    const int d0 = blockIdx.y * 64;
    const int t  = threadIdx.x;
    __shared__ f16 T[64][72];

    const float* Xb  = X  + ((size_t)b*NN + n0)*ND + d0;
    f16*         Xhb = Xh + ((size_t)b*NN + n0)*ND + d0;
    #pragma unroll
    for (int it = 0; it < 4; ++it) {
        int r  = it*16 + (t >> 4);
        int c4 = t & 15;
        float4 v = *(const float4*)(Xb + (size_t)r*ND + c4*4);
        f16x4 h; h[0]=(f16)v.x; h[1]=(f16)v.y; h[2]=(f16)v.z; h[3]=(f16)v.w;
        *(f16x4*)&Xhb[(size_t)r*ND + c4*4] = h;
        *(f16x4*)&T[r][c4*4] = h;
    }
    __syncthreads();
    f16* Xtb = Xt + ((size_t)b*ND + d0)*NN + n0;
    #pragma unroll
    for (int it = 0; it < 2; ++it) {
        int id = it*256 + t;
        int dr = id >> 3;
        int ch = id & 7;
        f16x8 v;
        #pragma unroll
        for (int u = 0; u < 8; ++u) v[u] = T[ch*8+u][dr];
        *(f16x8*)&Xtb[(size_t)dr*NN + ch*8] = v;
    }
}

// ---------------- split-KV flash kernel with swapped-QK in-lane softmax -----
// QK^T computed as mfma(K,Q) -> lane (c,g) holds S^T[j=4g+r][q=c] (s0: j<16,
// s1: j>=16). Softmax row q=c: 7 in-lane fmax + shfl_xor(16,32); m,l scalars.
// P repack to PV A-frag via 2 ds_write_b64 + 1 ds_read_b128 (40-f16 rows).
// PV = mfma(pf, vf) unchanged -> coalesced epilogue. sc/inv cross-lane via
// 4 ds_bpermute (q=c -> q=g*4+r).
__global__ __launch_bounds__(256, 2)
void attn8(const f16* __restrict__ Xh, const f16* __restrict__ Xt,
           const int* __restrict__ lenp,
           f16* __restrict__ Op, float* __restrict__ Sl)
{
    const int tid  = threadIdx.x;
    const int lane = tid & 63;
    const int w = tid >> 6;
    const int g = lane >> 4;
    const int c = lane & 15;

    // ---- job mapping: LPT + XCD pairing + KV-half split ----
    const bool is64 = (lenp[1] == 0);
    long long Lv[NB];
    #pragma unroll
    for (int i = 0; i < NB; ++i) Lv[i] = len_at(lenp, i, is64);
    const int x   = blockIdx.x & 7;
    const int kk2 = blockIdx.x >> 3;      // 0..127
    const int h   = kk2 & 1;              // KV half (tile parity)
    const int k2  = kk2 >> 1;             // 0..63
    const int wanted = (k2 < 32) ? x : (15 - x);
    const int qt  = k2 & 31;
    int bsel = 0; long long Lb = 1;
    #pragma unroll
    for (int bb = 0; bb < NB; ++bb) {
        int rk = 0;
        #pragma unroll
        for (int b2 = 0; b2 < NB; ++b2)
            rk += (Lv[b2] > Lv[bb]) || (Lv[b2] == Lv[bb] && b2 < bb);
        if (rk == wanted) { bsel = bb; Lb = Lv[bb]; }
    }
    const int nt  = (int)((Lb + KVB - 1) / KVB);
    const int nth = (h == 0) ? ((nt + 1) >> 1) : (nt >> 1);
    if (nth == 0) return;

    __shared__ f16 Kl[8192];        // 16KB single buffer
    __shared__ f16 Vl[8192];        // 16KB single buffer
    __shared__ f16 Pl[4][16*40];    // per-wave P repack, 80B rows (16B-aligned)

    const char* xhb = (const char*)(Xh + (size_t)bsel*NN*ND);
    const char* xtb = (const char*)(Xt + (size_t)bsel*ND*NN);

    // ---- Q fragments (B-operand of swapped QK): Q[q=base+c][kk*32+g*8+i] ----
    f16x8 qf[8];
    {
        const char* qp = xhb + (size_t)(qt*QB + w*16 + c)*512 + g*16;
        #pragma unroll
        for (int kk = 0; kk < 8; ++kk) qf[kk] = *(const f16x8*)(qp + kk*64);
    }

    auto stage_k = [&](int kv0) {
        char* kb = (char*)&Kl[0];
        #pragma unroll
        for (int it = 0; it < 4; ++it) {
            int S  = it*256 + tid;
            int kk = S >> 7, j = (S >> 2) & 31, gg = S & 3;
            gll16(xhb + (size_t)(kv0 + j)*512 + kk*64 + gg*16, kb + S*16);
        }
    };
    auto stage_v = [&](int kv0) {
        char* vb = (char*)&Vl[0];
        #pragma unroll
        for (int it = 0; it < 4; ++it) {
            int T  = it*256 + tid;
            int dt = T >> 6, cc = (T >> 2) & 15, gg = T & 3;
            gll16(xtb + (size_t)(dt*16 + cc)*4096 + (size_t)(kv0 + gg*8)*2, vb + T*16);
        }
    };

    f32x4 o[16];
    #pragma unroll
    for (int dt = 0; dt < 16; ++dt) o[dt] = (f32x4){0.f,0.f,0.f,0.f};
    float m = -INFINITY;
    float l = 0.f;

    f16* pw = &Pl[w][0];

    stage_k(h*KVB);
    stage_v(h*KVB);

    for (int ti = 0; ti < nth; ++ti) {
        const int kv0 = (2*ti + h) * KVB;
        const bool more = (ti + 1 < nth);

        asm volatile("s_waitcnt vmcnt(4)" ::: "memory");   // own K(t) landed
        __builtin_amdgcn_s_barrier();                      // K ready block-wide

        const char* kb = (const char*)&Kl[0];
        const char* vb = (const char*)&Vl[0];

        // ---- QK^T swapped: S^T[j][q], lane (c,g) reg r = S[q=c][j=4g+r|16+4g+r]
        f32x4 s0 = (f32x4){0.f,0.f,0.f,0.f};
        f32x4 s1 = (f32x4){0.f,0.f,0.f,0.f};
        __builtin_amdgcn_s_setprio(1);
        #pragma unroll
        for (int kk = 0; kk < 8; ++kk) {
            f16x8 b0 = *(const f16x8*)(kb + kk*2048        + c*64 + g*16);
            f16x8 b1 = *(const f16x8*)(kb + kk*2048 + 1024 + c*64 + g*16);
            s0 = __builtin_amdgcn_mfma_f32_16x16x32_f16(b0, qf[kk], s0, 0, 0, 0);
            s1 = __builtin_amdgcn_mfma_f32_16x16x32_f16(b1, qf[kk], s1, 0, 0, 0);
        }
        __builtin_amdgcn_s_setprio(0);

        asm volatile("s_waitcnt vmcnt(0)" ::: "memory");   // own V(t) landed
        __builtin_amdgcn_s_barrier();                      // V ready + K fully read
        if (more) stage_k(kv0 + 2*KVB);                    // overwrite K under SM/PV

        // ---- column mask: j = kv0 + 4g + r (s0), +16 (s1) ----
        const float NEG = -1e30f;
        if (kv0 + KVB > (int)Lb) {
            const int jb = kv0 + g*4;
            #pragma unroll
            for (int r = 0; r < 4; ++r) {
                if (jb + r >= Lb)      s0[r] = NEG;
                if (jb + 16 + r >= Lb) s1[r] = NEG;
            }
        }

        // ---- online softmax, row q=c: in-lane + 2 shuffles ----
        float tm = fmaxf(fmaxf(fmaxf(s0[0],s0[1]), fmaxf(s0[2],s0[3])),
                         fmaxf(fmaxf(s1[0],s1[1]), fmaxf(s1[2],s1[3])));
        tm = fmaxf(tm, __shfl_xor(tm, 16, 64));
        tm = fmaxf(tm, __shfl_xor(tm, 32, 64));
        if (__any(tm > m + 8.f)) {           // defer-max THR=8
            float mn = fmaxf(m, tm);
            float sc = __expf(m - mn);
            m = mn; l *= sc;
            float scr[4];
            #pragma unroll
            for (int r = 0; r < 4; ++r) scr[r] = bperm_f(g*4 + r, sc);
            #pragma unroll
            for (int dt = 0; dt < 16; ++dt) {
                o[dt][0]*=scr[0]; o[dt][1]*=scr[1]; o[dt][2]*=scr[2]; o[dt][3]*=scr[3];
            }
        }
        float p0[4], p1[4];
        #pragma unroll
        for (int r = 0; r < 4; ++r) {
            p0[r] = __expf(s0[r] - m);
            p1[r] = __expf(s1[r] - m);
        }
        float rs = ((p0[0]+p0[1]) + (p0[2]+p0[3])) + ((p1[0]+p1[1]) + (p1[2]+p1[3]));
        rs += __shfl_xor(rs, 16, 64);
        rs += __shfl_xor(rs, 32, 64);
        l += rs;

        // ---- P repack: write j=4g..4g+3 and 16+4g..+3, read j=8g..8g+7 ----
        f16x4 pa, pb;
        pa[0]=(f16)p0[0]; pa[1]=(f16)p0[1]; pa[2]=(f16)p0[2]; pa[3]=(f16)p0[3];
        pb[0]=(f16)p1[0]; pb[1]=(f16)p1[1]; pb[2]=(f16)p1[2]; pb[3]=(f16)p1[3];
        *(f16x4*)&pw[c*40 + 4*g]      = pa;
        *(f16x4*)&pw[c*40 + 16 + 4*g] = pb;
        f16x8 pf = *(const f16x8*)&pw[c*40 + 8*g];

        // ---- PV: O[16q x 256d], A=pf (P[q=c][j=8g+i]), B=vf ----
        __builtin_amdgcn_s_setprio(1);
        #pragma unroll
        for (int dt = 0; dt < 16; ++dt) {
            f16x8 vf = *(const f16x8*)(vb + dt*1024 + c*64 + g*16);
            o[dt] = __builtin_amdgcn_mfma_f32_16x16x32_f16(pf, vf, o[dt], 0, 0, 0);
        }
        __builtin_amdgcn_s_setprio(0);

        asm volatile("" ::: "memory");
        __builtin_amdgcn_s_barrier();                      // all done reading V(t)
        if (more) stage_v(kv0 + 2*KVB);
    }

    // ---- epilogue: normalized partial (f16) + per-row logsumexp (f32) ----
    float linv = 1.f / l;
    float inv[4];
    #pragma unroll
    for (int r = 0; r < 4; ++r) inv[r] = bperm_f(g*4 + r, linv);
    f16* op = Op + (size_t)h*XSZ + ((size_t)bsel*NN + (size_t)(qt*QB + w*16 + g*4))*ND + c;
    #pragma unroll
    for (int r = 0; r < 4; ++r) {
        #pragma unroll
        for (int dt = 0; dt < 16; ++dt)
            op[(size_t)r*ND + dt*16] = (f16)(o[dt][r] * inv[r]);
    }
    if (g == 0) {
        Sl[((size_t)(h*NB + bsel))*NN + (size_t)(qt*QB + w*16 + c)] = m + __logf(l);
    }
}

// ---------------- merge: out = (O1 w1 + O2 w2) / (w1 + w2) ------------------
__global__ __launch_bounds__(256)
void merge(const f16* __restrict__ Op, const float* __restrict__ Sl,
           const int* __restrict__ lenp, float* __restrict__ out)
{
    const int tid = threadIdx.x;
    const int rg  = blockIdx.x * 8 + (tid >> 5);   // global row 0..32767
    const int b   = rg >> 11;
    const int q   = rg & 2047;
    const int d0  = (tid & 31) * 8;

    const bool is64 = (lenp[1] == 0);
    const long long Lb = len_at(lenp, b, is64);

    const f16* p1 = Op + ((size_t)b*NN + q)*ND + d0;
    f16x8 a1 = *(const f16x8*)p1;
    float r[8];
    if (Lb <= KVB) {
        #pragma unroll
        for (int i = 0; i < 8; ++i) r[i] = (float)a1[i];
    } else {
        f16x8 a2 = *(const f16x8*)(p1 + XSZ);
        float s1 = Sl[(size_t)b*NN + q];
        float s2 = Sl[(size_t)(NB + b)*NN + q];
        float sm = fmaxf(s1, s2);
        float w1 = __expf(s1 - sm), w2 = __expf(s2 - sm);
        float dn = 1.f / (w1 + w2);
        w1 *= dn; w2 *= dn;
        #pragma unroll
        for (int i = 0; i < 8; ++i) r[i] = (float)a1[i]*w1 + (float)a2[i]*w2;
    }
    float* ob = out + ((size_t)b*NN + q)*ND + d0;
    *(float4*)ob       = (float4){r[0], r[1], r[2], r[3]};
    *(float4*)(ob + 4) = (float4){r[4], r[5], r[6], r[7]};
}

// ---------------- mid-tier (round-5 attn4, proven) --------------------------
__global__ __launch_bounds__(256, 2)
void attn4(const f16* __restrict__ Xh, const f16* __restrict__ Xt,
           const int* __restrict__ lenp, float* __restrict__ out)
{
    const int tid  = threadIdx.x;
    const int lane = tid & 63;
    const int w = tid >> 6;
    const int g = lane >> 4;
    const int c = lane & 15;

    const bool is64 = (lenp[1] == 0);
    long long Lv[NB];
    #pragma unroll
    for (int i = 0; i < NB; ++i) Lv[i] = len_at(lenp, i, is64);
    const int x = blockIdx.x & 7;
    const int k = blockIdx.x >> 3;
    const int wanted = (k < 32) ? x : (15 - x);
    const int qt = k & 31;
    int bsel = 0; long long Lb = 1;
    #pragma unroll
    for (int bb = 0; bb < NB; ++bb) {
        int rk = 0;
        #pragma unroll
        for (int b2 = 0; b2 < NB; ++b2)
            rk += (Lv[b2] > Lv[bb]) || (Lv[b2] == Lv[bb] && b2 < bb);
        if (rk == wanted) { bsel = bb; Lb = Lv[bb]; }
    }
    const int nt = (int)((Lb + KVB - 1) / KVB);

    __shared__ f16 Kl[2][8192];
    __shared__ f16 Vl[2][8192];
    __shared__ f16 Pl[4][16*36];

    const char* xhb = (const char*)(Xh + (size_t)bsel*NN*ND);
    const char* xtb = (const char*)(Xt + (size_t)bsel*ND*NN);

    f16x8 qf[8];
    {
        const char* qp = xhb + (size_t)(qt*QB + w*16 + c)*512 + g*16;
        #pragma unroll
        for (int kk = 0; kk < 8; ++kk) qf[kk] = *(const f16x8*)(qp + kk*64);
    }

    auto stage = [&](int buf, int kv0) {
        char* kb = (char*)&Kl[buf][0];
        char* vb = (char*)&Vl[buf][0];
        #pragma unroll
        for (int it = 0; it < 4; ++it) {
            int S  = it*256 + tid;
            int kk = S >> 7, j = (S >> 2) & 31, gg = S & 3;
            gll16(xhb + (size_t)(kv0 + j)*512 + kk*64 + gg*16, kb + S*16);
        }
        #pragma unroll
        for (int it = 0; it < 4; ++it) {
            int T  = it*256 + tid;
            int dt = T >> 6, cc = (T >> 2) & 15, gg = T & 3;
            gll16(xtb + (size_t)(dt*16 + cc)*4096 + (size_t)(kv0 + gg*8)*2, vb + T*16);
        }
    };

    f32x4 o[16];
    #pragma unroll
    for (int dt = 0; dt < 16; ++dt) o[dt] = (f32x4){0.f,0.f,0.f,0.f};
    float m[4] = {-INFINITY,-INFINITY,-INFINITY,-INFINITY};
    float l[4] = {0.f,0.f,0.f,0.f};

    f16* pw = &Pl[w][0];

    stage(0, 0);
    if (nt > 1) stage(1, KVB);

    for (int t = 0; t < nt; ++t) {
        const int kv0 = t * KVB;
        const int buf = t & 1;

        if (t + 1 < nt) { asm volatile("s_waitcnt vmcnt(8)" ::: "memory"); }
        else            { asm volatile("s_waitcnt vmcnt(0)" ::: "memory"); }
        __builtin_amdgcn_s_barrier();

        const char* kb = (const char*)&Kl[buf][0];
        const char* vb = (const char*)&Vl[buf][0];

        f32x4 s0 = (f32x4){0.f,0.f,0.f,0.f};
        f32x4 s1 = (f32x4){0.f,0.f,0.f,0.f};
        #pragma unroll
        for (int kk = 0; kk < 8; ++kk) {
            f16x8 b0 = *(const f16x8*)(kb + kk*2048        + c*64 + g*16);
            f16x8 b1 = *(const f16x8*)(kb + kk*2048 + 1024 + c*64 + g*16);
            s0 = __builtin_amdgcn_mfma_f32_16x16x32_f16(qf[kk], b0, s0, 0, 0, 0);
            s1 = __builtin_amdgcn_mfma_f32_16x16x32_f16(qf[kk], b1, s1, 0, 0, 0);
        }

        const float NEG = -1e30f;
        if (kv0 + c >= Lb)      { s0[0]=NEG; s0[1]=NEG; s0[2]=NEG; s0[3]=NEG; }
        if (kv0 + 16 + c >= Lb) { s1[0]=NEG; s1[1]=NEG; s1[2]=NEG; s1[3]=NEG; }

        float mx[4], mn[4], sc[4], p0[4], p1[4], rs[4];
        #pragma unroll
        for (int r = 0; r < 4; ++r) mx[r] = fmaxf(s0[r], s1[r]);
        #pragma unroll
        for (int off = 8; off >= 1; off >>= 1) {
            #pragma unroll
            for (int r = 0; r < 4; ++r)
                mx[r] = fmaxf(mx[r], __shfl_xor(mx[r], off, 64));
        }
        #pragma unroll
        for (int r = 0; r < 4; ++r) {
            mn[r] = fmaxf(m[r], mx[r]);
            sc[r] = __expf(m[r] - mn[r]);
            p0[r] = __expf(s0[r] - mn[r]);
            p1[r] = __expf(s1[r] - mn[r]);
            rs[r] = p0[r] + p1[r];
        }
        #pragma unroll
        for (int off = 8; off >= 1; off >>= 1) {
            #pragma unroll
            for (int r = 0; r < 4; ++r)
                rs[r] += __shfl_xor(rs[r], off, 64);
        }
        bool chg = (sc[0]!=1.f) | (sc[1]!=1.f) | (sc[2]!=1.f) | (sc[3]!=1.f);
        if (__any(chg)) {
            #pragma unroll
            for (int dt = 0; dt < 16; ++dt) {
                o[dt][0]*=sc[0]; o[dt][1]*=sc[1]; o[dt][2]*=sc[2]; o[dt][3]*=sc[3];
            }
        }
        #pragma unroll
        for (int r = 0; r < 4; ++r) { l[r] = l[r]*sc[r] + rs[r]; m[r] = mn[r]; }

        #pragma unroll
        for (int r = 0; r < 4; ++r) {
            pw[(g*4+r)*36 + c]      = (f16)p0[r];
            pw[(g*4+r)*36 + 16 + c] = (f16)p1[r];
        }
        union { f16x4 hh[2]; f16x8 v; } pu;
        pu.hh[0] = *(const f16x4*)(pw + c*36 + g*8);
        pu.hh[1] = *(const f16x4*)(pw + c*36 + g*8 + 4);
        f16x8 pf = pu.v;

        #pragma unroll
        for (int dt = 0; dt < 16; ++dt) {
            f16x8 vf = *(const f16x8*)(vb + dt*1024 + c*64 + g*16);
            o[dt] = __builtin_amdgcn_mfma_f32_16x16x32_f16(pf, vf, o[dt], 0, 0, 0);
        }

        __builtin_amdgcn_s_barrier();
        if (t + 2 < nt) stage(buf, kv0 + 2*KVB);
    }

    float inv[4];
    #pragma unroll
    for (int r = 0; r < 4; ++r) inv[r] = 1.0f / l[r];
    float* ob = out + ((size_t)bsel*NN + (size_t)(qt*QB + w*16 + g*4))*ND + c;
    #pragma unroll
    for (int r = 0; r < 4; ++r) {
        #pragma unroll
        for (int dt = 0; dt < 16; ++dt)
            ob[(size_t)r*ND + dt*16] = o[dt][r] * inv[r];
    }
}

// ---------------- lowest tier (no workspace) --------------------------------
__global__ __launch_bounds__(256, 2)
void attn_fb(const float* __restrict__ X,
             const int* __restrict__ lenp,
             float* __restrict__ out)
{
    const int b   = blockIdx.y;
    const int qt  = blockIdx.x;
    const int tid = threadIdx.x;
    const int lane = tid & 63;
    const int w = tid >> 6;
    const int g = lane >> 4;
    const int c = lane & 15;

    const bool is64 = (lenp[1] == 0);
    const long long Lb = len_at(lenp, b, is64);

    __shared__ f16 Kl[KVB][264];
    __shared__ f16 Vt2[ND][40];
    __shared__ f16 Pl[4][16][40];

    const float* Xb = X + (size_t)b * NN * ND;

    f16x8 qf[8];
    {
        const float* qp = Xb + (size_t)(qt*64 + w*16 + c) * ND + g*8;
        #pragma unroll
        for (int kk = 0; kk < 8; ++kk) {
            float4 a = *(const float4*)(qp + kk*32);
            float4 d = *(const float4*)(qp + kk*32 + 4);
            f16x8 v;
            v[0]=(f16)a.x; v[1]=(f16)a.y; v[2]=(f16)a.z; v[3]=(f16)a.w;
            v[4]=(f16)d.x; v[5]=(f16)d.y; v[6]=(f16)d.z; v[7]=(f16)d.w;
            qf[kk] = v;
        }
    }

    f32x4 o[16];
    #pragma unroll
    for (int dt = 0; dt < 16; ++dt) o[dt] = (f32x4){0.f,0.f,0.f,0.f};
    float m[4] = {-INFINITY,-INFINITY,-INFINITY,-INFINITY};
    float lr[4] = {0.f,0.f,0.f,0.f};

    const int ntiles = (int)((Lb + KVB - 1) / KVB);
    for (int t = 0; t < ntiles; ++t) {
        const int kv0 = t * KVB;
        __syncthreads();
        #pragma unroll
        for (int it = 0; it < 8; ++it) {
            int idx4 = it*256 + tid;
            int row  = idx4 >> 6;
            int c4   = idx4 & 63;
            float4 v = *(const float4*)(Xb + (size_t)(kv0 + row)*ND + c4*4);
            f16x4 hh; hh[0]=(f16)v.x; hh[1]=(f16)v.y; hh[2]=(f16)v.z; hh[3]=(f16)v.w;
            *(f16x4*)&Kl[row][c4*4] = hh;
        }
        {
            const float* cp = Xb + (size_t)kv0*ND + tid;
            #pragma unroll
            for (int kq = 0; kq < 8; ++kq) {
                f16x4 hh;
                #pragma unroll
                for (int u = 0; u < 4; ++u) hh[u] = (f16)cp[(size_t)(kq*4+u)*ND];
                *(f16x4*)&Vt2[tid][kq*4] = hh;
            }
        }
        __syncthreads();

        f32x4 s0 = (f32x4){0.f,0.f,0.f,0.f};
        f32x4 s1 = (f32x4){0.f,0.f,0.f,0.f};
        #pragma unroll
        for (int kk = 0; kk < 8; ++kk) {
            f16x8 b0 = *(const f16x8*)&Kl[c     ][kk*32 + g*8];
            f16x8 b1 = *(const f16x8*)&Kl[16 + c][kk*32 + g*8];
            s0 = __builtin_amdgcn_mfma_f32_16x16x32_f16(qf[kk], b0, s0, 0, 0, 0);
            s1 = __builtin_amdgcn_mfma_f32_16x16x32_f16(qf[kk], b1, s1, 0, 0, 0);
        }

        const float NEG = -1e30f;
        if (kv0 + c >= Lb)      { s0[0]=NEG; s0[1]=NEG; s0[2]=NEG; s0[3]=NEG; }
        if (kv0 + 16 + c >= Lb) { s1[0]=NEG; s1[1]=NEG; s1[2]=NEG; s1[3]=NEG; }

        float mx[4], mn[4], sc[4], p0[4], p1[4], rs[4];
        #pragma unroll
        for (int r = 0; r < 4; ++r) mx[r] = fmaxf(s0[r], s1[r]);
        #pragma unroll
        for (int off = 8; off >= 1; off >>= 1) {
            #pragma unroll
            for (int r = 0; r < 4; ++r)
                mx[r] = fmaxf(mx[r], __shfl_xor(mx[r], off, 64));
        }
        #pragma unroll
        for (int r = 0; r < 4; ++r) {
            mn[r] = fmaxf(m[r], mx[r]);
            sc[r] = __expf(m[r] - mn[r]);
            p0[r] = __expf(s0[r] - mn[r]);
            p1[r] = __expf(s1[r] - mn[r]);
            rs[r] = p0[r] + p1[r];
        }
        #pragma unroll
        for (int off = 8; off >= 1; off >>= 1) {
            #pragma unroll
            for (int r = 0; r < 4; ++r)
                rs[r] += __shfl_xor(rs[r], off, 64);
        }
        bool chg = (sc[0]!=1.f) | (sc[1]!=1.f) | (sc[2]!=1.f) | (sc[3]!=1.f);
        if (__any(chg)) {
            #pragma unroll
            for (int dt = 0; dt < 16; ++dt) {
                o[dt][0]*=sc[0]; o[dt][1]*=sc[1]; o[dt][2]*=sc[2]; o[dt][3]*=sc[3];
            }
        }
        #pragma unroll
        for (int r = 0; r < 4; ++r) { lr[r] = lr[r]*sc[r] + rs[r]; m[r] = mn[r]; }

        #pragma unroll
        for (int r = 0; r < 4; ++r) {
            Pl[w][g*4+r][c]      = (f16)p0[r];
            Pl[w][g*4+r][16 + c] = (f16)p1[r];
        }
        f16x8 pf = *(const f16x8*)&Pl[w][c][g*8];

        #pragma unroll
        for (int dt = 0; dt < 16; ++dt) {
            f16x8 vf = *(const f16x8*)&Vt2[dt*16 + c][g*8];
            o[dt] = __builtin_amdgcn_mfma_f32_16x16x32_f16(pf, vf, o[dt], 0, 0, 0);
        }
    }

    float inv[4];
    #pragma unroll
    for (int r = 0; r < 4; ++r) inv[r] = 1.0f / lr[r];
    float* ob = out + ((size_t)b*NN + (size_t)(qt*64 + w*16 + g*4))*ND + c;
    #pragma unroll
    for (int r = 0; r < 4; ++r) {
        #pragma unroll
        for (int dt = 0; dt < 16; ++dt)
            ob[(size_t)r*ND + dt*16] = o[dt][r] * inv[r];
    }
}

extern "C" void kernel_launch(void* const* d_in, const int* in_sizes, int n_in,
                              void* d_out, int out_size, void* d_ws, size_t ws_size,
                              hipStream_t stream) {
    const float* X    = (const float*)d_in[0];
    const int*   lenp = (const int*)d_in[1];
    float*       out  = (float*)d_out;

    const size_t need_base  = XSZ * 2 * 2;                    // Xh + Xt (f16)
    const size_t need_split = need_base + XSZ * 2 * 2         // + Op[2] (f16)
                              + (size_t)2 * NB * NN * 4;      // + Sl (f32)
    if (ws_size >= need_split) {
        f16* Xh = (f16*)d_ws;
        f16* Xt = Xh + XSZ;
        f16* Op = Xt + XSZ;
        float* Sl = (float*)(Op + 2*XSZ);
        hipLaunchKernelGGL(prep, dim3(NN/64, ND/64, NB), dim3(256), 0, stream, X, Xh, Xt);
        hipLaunchKernelGGL(attn8, dim3(1024), dim3(256), 0, stream, Xh, Xt, lenp, Op, Sl);
        hipLaunchKernelGGL(merge, dim3(NB*NN/8), dim3(256), 0, stream, Op, Sl, lenp, out);
    } else if (ws_size >= need_base) {
        f16* Xh = (f16*)d_ws;
        f16* Xt = Xh + XSZ;
        hipLaunchKernelGGL(prep, dim3(NN/64, ND/64, NB), dim3(256), 0, stream, X, Xh, Xt);
        hipLaunchKernelGGL(attn4, dim3(512), dim3(256), 0, stream, Xh, Xt, lenp, out);
    } else {
        hipLaunchKernelGGL(attn_fb, dim3(NN/64, NB), dim3(256), 0, stream, X, lenp, out);
    }
}